// Round 3
// baseline (226.873 us; speedup 1.0000x reference)
//
#include <hip/hip_runtime.h>
#include <math.h>

#define NN 2048
#define BATCH 8
#define FDIM 128
#define MASKV -9000000000000000.0f

// ---------------- kernel 1: positional encoding table pe[2048][128] --------
__global__ void k_pe(float* __restrict__ pe) {
    int i = blockIdx.x * 256 + threadIdx.x;       // 0 .. 2048*128-1
    int n = i >> 7;
    int k = i & 127;
    int jj = k >> 1;
    float dt = expf((float)(2 * jj) * (-0.07195578415606394f)); // -ln(1e4)/128
    float ang = (float)n * dt;
    float decay = 1.f + expf(-(float)n * 0.01f);
    float v = ((k & 1) == 0 ? sinf(ang) : cosf(ang)) * decay;
    pe[i] = v;
}

// ---------------- kernel 2: Wh = (h+pe) @ W ; s1 = Wh@a1 ; s2 = Wh@a2 ------
// block: 256 threads -> 16 col-groups x 16 row-groups; 64 rows x 128 cols tile
__global__ __launch_bounds__(256) void k_wh(const float* __restrict__ h,
                                            const float* __restrict__ pe,
                                            const float* __restrict__ W,
                                            const float* __restrict__ a,
                                            float* __restrict__ Wh,
                                            float* __restrict__ s1,
                                            float* __restrict__ s2) {
    __shared__ float w_lds[64 * 128];     // W[kp*64 + k][c]
    __shared__ float hpe_lds[64 * 68];    // rows 64, stride 68 (bank pad)
    const int b  = blockIdx.y;
    const int n0 = blockIdx.x * 64;
    const int t  = threadIdx.x;
    const int tc = t & 15;                // col group -> cols tc*8..+7
    const int tr = t >> 4;                // row group -> rows tr*4..+3

    float acc[4][8];
#pragma unroll
    for (int i = 0; i < 4; i++)
#pragma unroll
        for (int j = 0; j < 8; j++) acc[i][j] = 0.f;

    for (int kp = 0; kp < 2; ++kp) {
        {
            const float4* wsrc = (const float4*)(W + kp * 64 * 128);
            float4* wdst = (float4*)w_lds;
#pragma unroll
            for (int q = 0; q < 8; q++) wdst[t + q * 256] = wsrc[t + q * 256];
        }
        {
#pragma unroll
            for (int q = 0; q < 4; q++) {
                int f = t + q * 256;          // float4 index 0..1023
                int r = f >> 4;               // row 0..63
                int k4 = (f & 15) << 2;       // k offset 0..60
                int n = n0 + r;
                int kk = kp * 64 + k4;
                const float* hp_src = h + ((size_t)b * NN + n) * FDIM + kk;
                float4 hv = *(const float4*)hp_src;
                float4 pv = *(const float4*)(pe + (size_t)n * FDIM + kk);
                float4 hpv = make_float4(hv.x + pv.x, hv.y + pv.y,
                                         hv.z + pv.z, hv.w + pv.w);
                *(float4*)(hpe_lds + r * 68 + k4) = hpv;
            }
        }
        __syncthreads();
#pragma unroll 4
        for (int k = 0; k < 64; k++) {
            float wv[8];
            float4 wa = *(float4*)(w_lds + k * 128 + tc * 8);
            float4 wb = *(float4*)(w_lds + k * 128 + tc * 8 + 4);
            wv[0] = wa.x; wv[1] = wa.y; wv[2] = wa.z; wv[3] = wa.w;
            wv[4] = wb.x; wv[5] = wb.y; wv[6] = wb.z; wv[7] = wb.w;
#pragma unroll
            for (int i = 0; i < 4; i++) {
                float hv = hpe_lds[(tr * 4 + i) * 68 + k];
#pragma unroll
                for (int j = 0; j < 8; j++) acc[i][j] = fmaf(hv, wv[j], acc[i][j]);
            }
        }
        __syncthreads();
    }

    float a1v[8], a2v[8];
#pragma unroll
    for (int j = 0; j < 8; j++) { a1v[j] = a[tc * 8 + j]; a2v[j] = a[FDIM + tc * 8 + j]; }
#pragma unroll
    for (int i = 0; i < 4; i++) {
        int n = n0 + tr * 4 + i;
        float* dst = Wh + ((size_t)b * NN + n) * FDIM + tc * 8;
        *(float4*)dst = make_float4(acc[i][0], acc[i][1], acc[i][2], acc[i][3]);
        *(float4*)(dst + 4) = make_float4(acc[i][4], acc[i][5], acc[i][6], acc[i][7]);
        float p1 = 0.f, p2 = 0.f;
#pragma unroll
        for (int j = 0; j < 8; j++) {
            p1 = fmaf(acc[i][j], a1v[j], p1);
            p2 = fmaf(acc[i][j], a2v[j], p2);
        }
#pragma unroll
        for (int off = 1; off < 16; off <<= 1) {
            p1 += __shfl_xor(p1, off, 64);
            p2 += __shfl_xor(p2, off, 64);
        }
        if (tc == 0) {
            s1[(size_t)b * NN + n] = p1;
            s2[(size_t)b * NN + n] = p2;
        }
    }
}

// ---------------- kernel 3: stream adj, row softmax, column-sum partials ---
// grid (128 chunks of 16 rows, 8 b), 256 threads = 4 waves, 4 rows per wave.
// No atomics: block writes its 2048-wide partial column-sum to c_part.
__global__ __launch_bounds__(256) void k_attn(const float* __restrict__ adj,
                                              const float* __restrict__ s1,
                                              const float* __restrict__ s2,
                                              float* __restrict__ c_part) {
    const int b = blockIdx.y;
    const int chunk = blockIdx.x;      // 16 rows per chunk
    const int t = threadIdx.x;
    const int wave = t >> 6;
    const int lane = t & 63;
    __shared__ float c_lds[4][NN];     // 32 KB

    const float* s2b = s2 + (size_t)b * NN;
    float s2v[32];
#pragma unroll
    for (int kq = 0; kq < 8; kq++) {
        float4 v = *(const float4*)(s2b + kq * 256 + lane * 4);
        s2v[kq * 4 + 0] = v.x; s2v[kq * 4 + 1] = v.y;
        s2v[kq * 4 + 2] = v.z; s2v[kq * 4 + 3] = v.w;
    }
    float c_acc[32];
#pragma unroll
    for (int j = 0; j < 32; j++) c_acc[j] = 0.f;

    const int nbase = chunk * 16;
    const float* adjb = adj + (size_t)b * NN * NN;
    const float* s1b = s1 + (size_t)b * NN;

#pragma unroll 1
    for (int ri = 0; ri < 4; ri++) {
        int n = nbase + wave * 4 + ri;
        if (n == 0) continue;          // valid[:,0] = False -> row 0 never used
        float s1n = s1b[n];
        const float* arow = adjb + (size_t)n * NN;
        float val[32];
        float vmax = MASKV;
#pragma unroll
        for (int kq = 0; kq < 8; kq++) {
            float4 av = *(const float4*)(arow + kq * 256 + lane * 4);
            float a4[4] = {av.x, av.y, av.z, av.w};
#pragma unroll
            for (int e = 0; e < 4; e++) {
                int m = kq * 256 + lane * 4 + e;
                float x = s1n + s2v[kq * 4 + e];
                float ev = fmaxf(x, 0.2f * x);           // LeakyReLU, alpha<1
                bool conn = (a4[e] > 0.f) || (m == n);   // forced diagonal
                float v = conn ? ev : MASKV;
                val[kq * 4 + e] = v;
                vmax = fmaxf(vmax, v);
            }
        }
#pragma unroll
        for (int off = 32; off; off >>= 1) vmax = fmaxf(vmax, __shfl_xor(vmax, off, 64));
        float zsum = 0.f;
#pragma unroll
        for (int j = 0; j < 32; j++) {
            float p = __expf(val[j] - vmax);   // masked -> exp(-huge) == 0
            val[j] = p;
            zsum += p;
        }
#pragma unroll
        for (int off = 32; off; off >>= 1) zsum += __shfl_xor(zsum, off, 64);
        float rz = 1.f / zsum;
#pragma unroll
        for (int j = 0; j < 32; j++) c_acc[j] = fmaf(val[j], rz, c_acc[j]);
    }

    // each wave stores its accumulator; parallel cross-wave reduce; one store
#pragma unroll
    for (int kq = 0; kq < 8; kq++)
        *(float4*)(&c_lds[wave][kq * 256 + lane * 4]) =
            make_float4(c_acc[kq * 4 + 0], c_acc[kq * 4 + 1],
                        c_acc[kq * 4 + 2], c_acc[kq * 4 + 3]);
    __syncthreads();
    float* dst = c_part + ((size_t)b * 128 + chunk) * NN;
#pragma unroll
    for (int q = 0; q < 2; q++) {
        int idx = t + q * 256;   // float4 index 0..511
        float4 v0 = ((float4*)c_lds[0])[idx];
        float4 v1 = ((float4*)c_lds[1])[idx];
        float4 v2 = ((float4*)c_lds[2])[idx];
        float4 v3 = ((float4*)c_lds[3])[idx];
        ((float4*)dst)[idx] = make_float4(v0.x + v1.x + v2.x + v3.x,
                                          v0.y + v1.y + v2.y + v3.y,
                                          v0.z + v1.z + v2.z + v3.z,
                                          v0.w + v1.w + v2.w + v3.w);
    }
}

// ---------------- kernel 4: reduce c_part + g_part = c^T * Wh partials -----
// grid (32 m-chunks of 64, 8 b), 256 threads
__global__ __launch_bounds__(256) void k_gpre(const float* __restrict__ Wh,
                                              const float* __restrict__ c_part,
                                              float* __restrict__ g_part) {
    const int b = blockIdx.y;
    const int mc = blockIdx.x;
    const int m0 = mc * 64;
    const int t = threadIdx.x;
    __shared__ float red[256];
    __shared__ float c_lds[64];

    // phase 1: c[b][m0+mi] = sum over 128 chunk-partials (4 waves split chunks)
    {
        const int mi = t & 63;
        const int w = t >> 6;
        const float* cp = c_part + (size_t)b * 128 * NN + m0 + mi;
        float s = 0.f;
#pragma unroll 8
        for (int j = 0; j < 32; j++) s += cp[(size_t)(w * 32 + j) * NN];
        red[w * 64 + mi] = s;
    }
    __syncthreads();
    if (t < 64) c_lds[t] = red[t] + red[t + 64] + red[t + 128] + red[t + 192];
    __syncthreads();

    // phase 2: partial g over this m-chunk
    const int o = t & 127;
    const int mh = t >> 7;              // 0/1
    float acc = 0.f;
    const float* whb = Wh + ((size_t)b * NN + m0 + mh * 32) * FDIM;
#pragma unroll 4
    for (int mm = 0; mm < 32; mm++)
        acc = fmaf(c_lds[mh * 32 + mm], whb[mm * FDIM + o], acc);
    g_part[((size_t)(mc * 2 + mh)) * (BATCH * FDIM) + b * FDIM + o] = acc;
}

// ---------------- kernel 5: out = elu( (sum of 64 partials) / 2047 ) -------
__global__ void k_elu(const float* __restrict__ g_part, float* __restrict__ out) {
    int i = blockIdx.x * 256 + threadIdx.x;    // 0..1023 = b*128+o
    if (i < BATCH * FDIM) {
        float s = 0.f;
#pragma unroll 8
        for (int p = 0; p < 64; p++) s += g_part[p * (BATCH * FDIM) + i];
        float g = s * (1.0f / 2047.0f);
        out[i] = g > 0.f ? g : expm1f(g);
    }
}

extern "C" void kernel_launch(void* const* d_in, const int* in_sizes, int n_in,
                              void* d_out, int out_size, void* d_ws, size_t ws_size,
                              hipStream_t stream) {
    (void)in_sizes; (void)n_in; (void)out_size; (void)ws_size;
    const float* h   = (const float*)d_in[0];
    const float* adj = (const float*)d_in[1];
    const float* W   = (const float*)d_in[2];
    const float* a   = (const float*)d_in[3];
    float* out = (float*)d_out;

    char* ws = (char*)d_ws;
    float* Wh     = (float*)ws;                                   // 8*2048*128
    float* pe     = Wh + (size_t)BATCH * NN * FDIM;               // 2048*128
    float* s1     = pe + (size_t)NN * FDIM;                       // 8*2048
    float* s2     = s1 + (size_t)BATCH * NN;                      // 8*2048
    float* c_part = s2 + (size_t)BATCH * NN;                      // 8*128*2048
    float* g_part = c_part + (size_t)BATCH * 128 * NN;            // 64*8*128

    hipLaunchKernelGGL(k_pe, dim3(NN * FDIM / 256), dim3(256), 0, stream, pe);
    hipLaunchKernelGGL(k_wh, dim3(NN / 64, BATCH), dim3(256), 0, stream,
                       h, pe, W, a, Wh, s1, s2);
    hipLaunchKernelGGL(k_attn, dim3(NN / 16, BATCH), dim3(256), 0, stream,
                       adj, s1, s2, c_part);
    hipLaunchKernelGGL(k_gpre, dim3(NN / 64, BATCH), dim3(256), 0, stream,
                       Wh, c_part, g_part);
    hipLaunchKernelGGL(k_elu, dim3(4), dim3(256), 0, stream, g_part, out);
}